// Round 18
// baseline (499.238 us; speedup 1.0000x reference)
//
#include <hip/hip_runtime.h>
#include <hip/hip_fp16.h>

typedef unsigned short ushort_t;
typedef unsigned int uint_t;
typedef __attribute__((ext_vector_type(8))) _Float16 half8;
typedef __attribute__((ext_vector_type(4))) float f32x4;

#define NN 50000
#define NE 800000
#define NGR 256

// async global->LDS, 16B per lane; LDS dest = wave-uniform base + lane*16
typedef __attribute__((address_space(3))) unsigned int as3_u32;
typedef const __attribute__((address_space(1))) unsigned int as1_u32c;
__device__ __forceinline__ void gld16(const ushort_t* g, void* lds_base) {
    __builtin_amdgcn_global_load_lds((as1_u32c*)g, (as3_u32*)lds_base, 16, 0, 0);
}

// ---------------- CSR build ----------------
__global__ void k_scan1(const int* __restrict__ deg, int* __restrict__ rowp,
                        int* __restrict__ bsum, int M) {
    __shared__ int sm[256];
    int t = threadIdx.x, i = blockIdx.x * 256 + t;
    int v = (i < M) ? deg[i] + 1 : 0;   // +1 self loop
    sm[t] = v; __syncthreads();
    for (int off = 1; off < 256; off <<= 1) {
        int x = (t >= off) ? sm[t - off] : 0;
        __syncthreads();
        sm[t] += x;
        __syncthreads();
    }
    if (i < M) rowp[i] = sm[t] - v;     // exclusive
    if (t == 255) bsum[blockIdx.x] = sm[255];
}

__global__ void k_scan2(int* bsum, int NB) {
    __shared__ int sm[256];
    int t = threadIdx.x;
    int v = (t < NB) ? bsum[t] : 0;
    sm[t] = v; __syncthreads();
    for (int off = 1; off < 256; off <<= 1) {
        int x = (t >= off) ? sm[t - off] : 0;
        __syncthreads();
        sm[t] += x;
        __syncthreads();
    }
    if (t < NB) bsum[t] = sm[t] - v;    // exclusive block offsets
}

// also zeroes cur for the fill phase
__global__ void k_scan3(int* rowp, const int* __restrict__ bsum, int* __restrict__ cur,
                        int M, int total) {
    int i = blockIdx.x * 256 + threadIdx.x;
    if (i < M) { rowp[i] += bsum[blockIdx.x]; cur[i] = 0; }
    if (i == 0) rowp[M] = total;
}

// ---- fused prep: x cast -> fp16, weights -> transposed fp16, edge-degree count ----
__global__ void k_prep(const float* __restrict__ x0, __half* __restrict__ xf,
                       const float* __restrict__ W0, const float* __restrict__ W1,
                       const float* __restrict__ W2, __half* __restrict__ th,
                       const int* __restrict__ edst, int* __restrict__ deg) {
    int i = blockIdx.x * 256 + threadIdx.x;
    if (i < 1600000) {
        float4 v = ((const float4*)x0)[i];
        __half2 a = __floats2half2_rn(v.x, v.y);
        __half2 b = __floats2half2_rn(v.z, v.w);
        *(__half2*)(xf + i * 4) = a;
        *(__half2*)(xf + i * 4 + 2) = b;
    } else if (i < 1600000 + 114688) {
        int w = i - 1600000;
        const float* W; int K, NC, idx, base;
        if (w < 32768)      { W = W0; K = 128; NC = 256; idx = w;         base = 0; }
        else if (w < 98304) { W = W1; K = 256; NC = 256; idx = w - 32768; base = 32768; }
        else                { W = W2; K = 256; NC = 64;  idx = w - 98304; base = 98304; }
        int k = idx / NC, n = idx % NC;
        th[base + n * K + k] = __float2half(W[idx]);
    } else if (i < 1600000 + 114688 + NE) {
        atomicAdd(&deg[edst[i - 1714688]], 1);
    }
}

// ------- GEMM body (fp16 single-term) + fused attention-logit epilogue -------
template<int KD, int BN>
__device__ __forceinline__ void gemm_body(int bx, int by,
    const __half* __restrict__ Ax, const __half* __restrict__ Bth,
    __half* __restrict__ Hout, const float* __restrict__ a_s,
    const float* __restrict__ a_d, float* __restrict__ als,
    float* __restrict__ ald, int H, int M, int NC) {
    constexpr int BM = 128, BK = 32;
    __shared__ ushort_t sA[BM * BK];
    __shared__ ushort_t sB[BN * BK];
    const int tid = threadIdx.x;
    const int m0 = bx * BM;
    const int n0 = by * BN;
    const int wv = tid >> 6, ln = tid & 63;
    const int lrow = ln & 15, lq = ln >> 4;
    constexpr int RT = (BN == 128) ? 4 : 2;
    int wm, wn;
    if constexpr (BN == 128) { wm = (wv >> 1) * 64; wn = (wv & 1) * 64; }
    else                     { wm = wv * 32;        wn = 0; }
    const int roff = ln >> 2;
    const int coff = (ln & 3) * 8;

    f32x4 acc[RT][4] = {};

    for (int k0 = 0; k0 < KD; k0 += BK) {
        #pragma unroll
        for (int ch = 0; ch < 2; ++ch) {
            int rb = wv * 32 + ch * 16;
            size_t ga = (size_t)(m0 + rb + roff) * KD + k0 + coff;
            gld16((const ushort_t*)Ax + ga, &sA[rb * BK]);
        }
        if constexpr (BN == 128) {
            #pragma unroll
            for (int ch = 0; ch < 2; ++ch) {
                int rb = wv * 32 + ch * 16;
                size_t gb = (size_t)(n0 + rb + roff) * KD + k0 + coff;
                gld16((const ushort_t*)Bth + gb, &sB[rb * BK]);
            }
        } else {
            int rb = wv * 16;
            size_t gb = (size_t)(n0 + rb + roff) * KD + k0 + coff;
            gld16((const ushort_t*)Bth + gb, &sB[rb * BK]);
        }
        __syncthreads();
        half8 af[RT], bf[4];
        #pragma unroll
        for (int r = 0; r < RT; ++r)
            af[r] = *(const half8*)&sA[(wm + r * 16 + lrow) * BK + lq * 8];
        #pragma unroll
        for (int c = 0; c < 4; ++c)
            bf[c] = *(const half8*)&sB[(wn + c * 16 + lrow) * BK + lq * 8];
        #pragma unroll
        for (int r = 0; r < RT; ++r)
            #pragma unroll
            for (int c = 0; c < 4; ++c)
                acc[r][c] = __builtin_amdgcn_mfma_f32_16x16x32_f16(af[r], bf[c], acc[r][c], 0, 0, 0);
        __syncthreads();
    }
    // H-store (C/D layout: col=lane&15, row=(lane>>4)*4+reg)
    #pragma unroll
    for (int r = 0; r < RT; ++r) {
        #pragma unroll
        for (int c = 0; c < 4; ++c) {
            int colg = n0 + wn + c * 16 + lrow;
            #pragma unroll
            for (int j = 0; j < 4; ++j) {
                int row = m0 + wm + r * 16 + lq * 4 + j;
                if (row < M) Hout[(size_t)row * NC + colg] = __float2half(acc[r][c][j]);
            }
        }
    }
    // fused attention logits: this wave's 64 cols lie in exactly one head
    int hh = (n0 + wn) >> 6;
    float asv[4], adv[4];
    #pragma unroll
    for (int c = 0; c < 4; ++c) {
        int cg = (n0 + wn + c * 16 + lrow) & 63;
        asv[c] = a_s[hh * 64 + cg];
        adv[c] = a_d[hh * 64 + cg];
    }
    #pragma unroll
    for (int r = 0; r < RT; ++r) {
        #pragma unroll
        for (int j = 0; j < 4; ++j) {
            float ts = 0.f, td = 0.f;
            #pragma unroll
            for (int c = 0; c < 4; ++c) {
                float v = acc[r][c][j];
                ts += v * asv[c];
                td += v * adv[c];
            }
            #pragma unroll
            for (int m = 1; m < 16; m <<= 1) {
                ts += __shfl_xor(ts, m);
                td += __shfl_xor(td, m);
            }
            int row = m0 + wm + r * 16 + lq * 4 + j;
            if (lrow == 0 && row < M) {
                als[row * H + hh] = ts;
                ald[row * H + hh] = td;
            }
        }
    }
}

template<int KD, int BN>
__global__ __launch_bounds__(256)
void k_mgemm(const __half* __restrict__ Ax, const __half* __restrict__ Bth,
             __half* __restrict__ Hout,
             const float* __restrict__ a_s, const float* __restrict__ a_d,
             float* __restrict__ als, float* __restrict__ ald,
             int H, int M, int NC) {
    gemm_body<KD, BN>(blockIdx.x, blockIdx.y, Ax, Bth, Hout, a_s, a_d, als, ald, H, M, NC);
}

// ---- co-scheduled GEMM-L0 + CSR fill: blocks [0,782) gemm, rest fill ----
__global__ __launch_bounds__(256)
void k_gf(const __half* __restrict__ Ax, const __half* __restrict__ Bth,
          __half* __restrict__ Hout,
          const float* __restrict__ a_s, const float* __restrict__ a_d,
          float* __restrict__ als, float* __restrict__ ald, int M,
          const int* __restrict__ esrc, const int* __restrict__ edst,
          const int* __restrict__ rowp, int* __restrict__ cur,
          int* __restrict__ colv) {
    if (blockIdx.x < 782) {
        gemm_body<128, 128>(blockIdx.x >> 1, blockIdx.x & 1, Ax, Bth, Hout,
                            a_s, a_d, als, ald, 4, M, 256);
    } else {
        int i = (blockIdx.x - 782) * 256 + threadIdx.x;
        if (i < NE) {
            int d = edst[i];
            int pos = rowp[d] + atomicAdd(&cur[d], 1);
            colv[pos] = esrc[i];
        } else if (i < NE + NN) {
            int nn = i - NE;
            int pos = rowp[nn] + atomicAdd(&cur[nn], 1);
            colv[pos] = nn;
        }
    }
}

// ---- aggregation with in-kernel softmax (alpha in LDS) + bias + BN + ELU ----
// Phase 1 (per wave/node): alpha = exp(lrelu(als[s]+ald[n])) -> LDS fp16; den butterfly.
// Phase 2: gather loop, alpha from LDS (CAP overflow: recompute inline).
// H=4: 2 edges x 32 lanes (x4 unroll);  H=1: 8 edges x 8 lanes (x2 unroll).
#define CAP 192
template<int H, bool SPLIT>
__global__ __launch_bounds__(256)
void k_agg(const __half* __restrict__ h, const float* __restrict__ als,
           const float* __restrict__ ald, const int* __restrict__ rowp,
           const int* __restrict__ colv,
           const float* __restrict__ bias, const float* __restrict__ gam,
           const float* __restrict__ bet, const float* __restrict__ mu,
           const float* __restrict__ var,
           __half* __restrict__ xo, float* __restrict__ xf, int M) {
    constexpr int HC = H * 64;
    constexpr int EG = 512 / HC;        // edge groups: 2 (H=4), 8 (H=1)
    constexpr int L  = 64 / EG;         // lanes per edge: 32, 8
    constexpr int UN = (H == 4) ? 4 : 2;
    __shared__ ushort_t alf[4][CAP * H];
    int node = blockIdx.x * 4 + (threadIdx.x >> 6);
    if (node >= M) return;
    int w = threadIdx.x >> 6;
    int lane = threadIdx.x & 63;
    int rs = rowp[node], re = rowp[node + 1];
    int l = lane & (L - 1), eg = lane / L;
    int hB = (l * 8) >> 6;
    float inv, adB;
    if constexpr (H == 4) {
        float4 ad4 = *(const float4*)(ald + node * 4);
        float d0 = 0.f, d1 = 0.f, d2 = 0.f, d3 = 0.f;
        for (int i = rs + lane; i < re; i += 64) {
            int s = colv[i];
            float4 av = *(const float4*)(als + s * 4);
            float e0 = av.x + ad4.x; e0 = e0 > 0.f ? e0 : 0.2f * e0; e0 = __expf(e0);
            float e1 = av.y + ad4.y; e1 = e1 > 0.f ? e1 : 0.2f * e1; e1 = __expf(e1);
            float e2 = av.z + ad4.z; e2 = e2 > 0.f ? e2 : 0.2f * e2; e2 = __expf(e2);
            float e3 = av.w + ad4.w; e3 = e3 > 0.f ? e3 : 0.2f * e3; e3 = __expf(e3);
            d0 += e0; d1 += e1; d2 += e2; d3 += e3;
            int o = i - rs;
            if (o < CAP) {
                __half2 p0 = __floats2half2_rn(e0, e1);
                __half2 p1 = __floats2half2_rn(e2, e3);
                uint2 pk;
                pk.x = *(uint_t*)&p0; pk.y = *(uint_t*)&p1;
                *(uint2*)&alf[w][o * 4] = pk;
            }
        }
        #pragma unroll
        for (int off = 1; off < 64; off <<= 1) {
            d0 += __shfl_xor(d0, off); d1 += __shfl_xor(d1, off);
            d2 += __shfl_xor(d2, off); d3 += __shfl_xor(d3, off);
        }
        float den = (hB == 0) ? d0 : (hB == 1) ? d1 : (hB == 2) ? d2 : d3;
        inv = 1.f / (den + 1e-16f);
        adB = ((const float*)&ad4)[hB];
    } else {
        float ad = ald[node];
        float d = 0.f;
        for (int i = rs + lane; i < re; i += 64) {
            int s = colv[i];
            float e = als[s] + ad; e = e > 0.f ? e : 0.2f * e; e = __expf(e);
            d += e;
            int o = i - rs;
            if (o < CAP) alf[w][o] = __half_as_ushort(__float2half(e));
        }
        #pragma unroll
        for (int off = 1; off < 64; off <<= 1) d += __shfl_xor(d, off);
        inv = 1.f / (d + 1e-16f);
        adB = ad;
    }
    // phase 2: gather
    float acc[8] = {};
    for (int i = rs; i < re; i += EG * UN) {
        #pragma unroll
        for (int k = 0; k < UN; ++k) {
            int idx = i + eg + k * EG;
            bool vld = idx < re;
            int idx2 = vld ? idx : rs;
            int s = colv[idx2];
            int o = idx2 - rs;
            float a;
            if (o < CAP) {
                ushort_t abits;
                if constexpr (H == 4) abits = alf[w][o * 4 + hB];
                else                  abits = alf[w][o];
                a = __half2float(__ushort_as_half(abits));
            } else {
                float e = ((H == 4) ? als[s * 4 + hB] : als[s]) + adB;
                e = e > 0.f ? e : 0.2f * e;
                a = __expf(e);
            }
            a = vld ? a : 0.f;
            uint4 hv = *(const uint4*)(h + (size_t)s * HC + l * 8);
            const __half* hp = (const __half*)&hv;
            #pragma unroll
            for (int j = 0; j < 8; ++j)
                acc[j] = fmaf(a, __half2float(hp[j]), acc[j]);
        }
    }
    #pragma unroll
    for (int off = L; off < 64; off <<= 1) {
        #pragma unroll
        for (int j = 0; j < 8; ++j) acc[j] += __shfl_xor(acc[j], off);
    }
    if (eg == 0) {
        float fo[8];
        #pragma unroll
        for (int j = 0; j < 8; ++j) {
            int d = l * 8 + j;
            float o = acc[j] * inv + bias[d];
            float bn = (o - mu[d]) * rsqrtf(var[d] + 1e-5f) * gam[d] + bet[d];
            fo[j] = bn > 0.f ? bn : (__expf(bn) - 1.f);
        }
        if constexpr (SPLIT) {
            __half2 p0 = __floats2half2_rn(fo[0], fo[1]);
            __half2 p1 = __floats2half2_rn(fo[2], fo[3]);
            __half2 p2 = __floats2half2_rn(fo[4], fo[5]);
            __half2 p3 = __floats2half2_rn(fo[6], fo[7]);
            uint4 pk;
            pk.x = *(uint_t*)&p0; pk.y = *(uint_t*)&p1;
            pk.z = *(uint_t*)&p2; pk.w = *(uint_t*)&p3;
            *(uint4*)&xo[(size_t)node * HC + l * 8] = pk;
        } else {
            *(float4*)&xf[(size_t)node * HC + l * 8] = make_float4(fo[0], fo[1], fo[2], fo[3]);
            *(float4*)&xf[(size_t)node * HC + l * 8 + 4] = make_float4(fo[4], fo[5], fo[6], fo[7]);
        }
    }
}

// ---- fused pooling + MLP: 512 threads = 8 node-subsets x 64 dims, LDS reduce ----
__global__ __launch_bounds__(512)
void k_poolfc(const float* __restrict__ x, const int* __restrict__ batch,
              const float* __restrict__ fc1w, const float* __restrict__ fc1b,
              const float* __restrict__ fc2w, const float* __restrict__ fc2b,
              const float* __restrict__ fc3w, const float* __restrict__ fc3b,
              float* __restrict__ out, int M) {
    __shared__ float ssum[8][64];
    __shared__ float smax[8][64];
    __shared__ float hb[192];
    __shared__ float h1[64];
    __shared__ float h2[32];
    int g = blockIdx.x, t = threadIdx.x;
    int d = t & 63, sub = t >> 6;    // 8 subsets
    int lo = 0, hi = M;
    while (lo < hi) { int mid = (lo + hi) >> 1; if (batch[mid] < g) lo = mid + 1; else hi = mid; }
    int s = lo;
    lo = 0; hi = M;
    while (lo < hi) { int mid = (lo + hi) >> 1; if (batch[mid] < g + 1) lo = mid + 1; else hi = mid; }
    int e = lo;
    float sum = 0.f, mx = -3.0e38f;
    for (int n = s + sub; n < e; n += 8) {
        float v = x[(size_t)n * 64 + d];
        sum += v; mx = fmaxf(mx, v);
    }
    ssum[sub][d] = sum; smax[sub][d] = mx;
    __syncthreads();
    if (t < 64) {
        float sm = 0.f, m2 = -3.0e38f;
        #pragma unroll
        for (int k = 0; k < 8; ++k) { sm += ssum[k][t]; m2 = fmaxf(m2, smax[k][t]); }
        int cnt = e - s;
        hb[t] = sm / (float)(cnt > 1 ? cnt : 1);
        hb[64 + t] = (cnt == 0) ? 0.f : m2;
        hb[128 + t] = sm;
    }
    __syncthreads();
    if (t < 64) {
        float s1 = fc1b[t];
        for (int k = 0; k < 192; ++k) s1 += hb[k] * fc1w[k * 64 + t];
        h1[t] = fmaxf(s1, 0.f);
    }
    __syncthreads();
    if (t < 32) {
        float s2 = fc2b[t];
        for (int k = 0; k < 64; ++k) s2 += h1[k] * fc2w[k * 32 + t];
        h2[t] = fmaxf(s2, 0.f);
    }
    __syncthreads();
    if (t == 0) {
        float s3 = fc3b[0];
        for (int k = 0; k < 32; ++k) s3 += h2[k] * fc3w[k];
        out[g] = s3;
    }
}

extern "C" void kernel_launch(void* const* d_in, const int* in_sizes, int n_in,
                              void* d_out, int out_size, void* d_ws, size_t ws_size,
                              hipStream_t stream) {
    const float* x0     = (const float*)d_in[0];
    const int* ei       = (const int*)d_in[1];
    const int* batch    = (const int*)d_in[2];
    const float* W[3]   = {(const float*)d_in[3],  (const float*)d_in[11], (const float*)d_in[19]};
    const float* AS[3]  = {(const float*)d_in[4],  (const float*)d_in[12], (const float*)d_in[20]};
    const float* AD[3]  = {(const float*)d_in[5],  (const float*)d_in[13], (const float*)d_in[21]};
    const float* BI[3]  = {(const float*)d_in[6],  (const float*)d_in[14], (const float*)d_in[22]};
    const float* GA[3]  = {(const float*)d_in[7],  (const float*)d_in[15], (const float*)d_in[23]};
    const float* BE[3]  = {(const float*)d_in[8],  (const float*)d_in[16], (const float*)d_in[24]};
    const float* MU[3]  = {(const float*)d_in[9],  (const float*)d_in[17], (const float*)d_in[25]};
    const float* VA[3]  = {(const float*)d_in[10], (const float*)d_in[18], (const float*)d_in[26]};
    const float* fc1w = (const float*)d_in[27];
    const float* fc1b = (const float*)d_in[28];
    const float* fc2w = (const float*)d_in[29];
    const float* fc2b = (const float*)d_in[30];
    const float* fc3w = (const float*)d_in[31];
    const float* fc3b = (const float*)d_in[32];

    // top of use = 69,885,760 B (< 108,953,600 B proven safe).
    // cur has a DEDICATED region (k_gf runs fill concurrently with GEMM-L0).
    char* ws = (char*)d_ws;
    int*   rowp   = (int*)  (ws);                      // 200,004 B
    int*   colv   = (int*)  (ws + 200704);             // 3,400,000 B
    int*   bsum   = (int*)  (ws + 3600704);            // 1,024 B
    float* als    = (float*)(ws + 3602432);            // 800,000 B
    float* ald    = (float*)(ws + 4402432);            // 800,000 B
    __half* wTh   = (__half*)(ws + 5202432);           // 229,376 B (3 layers packed)
    __half* h_buf = (__half*)(ws + 5661184);           // 25,600,000 B
    __half* xf16  = (__half*)(ws + 31261184);          // 25,624,576 B (50048 rows x 256)
    float* xpool  = (float*)(ws + 56885760);           // 12,800,000 B
    int*   cur    = (int*)  (ws + 69685760);           // 200,000 B -> 69,885,760 B

    const int* esrc = ei;
    const int* edst = ei + NE;
    const int NB_SCAN = (NN + 255) / 256; // 196

    // prep (x cast + W split + deg count; cur zeroed first)
    hipMemsetAsync(cur, 0, NN * sizeof(int), stream);
    k_prep<<<(1600000 + 114688 + NE + 255) / 256, 256, 0, stream>>>(x0, xf16, W[0], W[1], W[2],
                                                                    wTh, edst, cur);
    // CSR scan (fill is co-scheduled with GEMM L0 below)
    k_scan1<<<NB_SCAN, 256, 0, stream>>>(cur, rowp, bsum, NN);
    k_scan2<<<1, 256, 0, stream>>>(bsum, NB_SCAN);
    k_scan3<<<NB_SCAN, 256, 0, stream>>>(rowp, bsum, cur, NN, NE + NN);

    const int GB = (NN + 127) / 128; // 391
    const int FILLB = (NE + NN + 255) / 256; // 3321
    int nwb = (NN + 3) / 4;          // 12500

    // ---- layer 0 (K=128, HC=256, H=4): GEMM co-scheduled with CSR fill
    k_gf<<<782 + FILLB, 256, 0, stream>>>(xf16, wTh, h_buf, AS[0], AD[0], als, ald, NN,
                                          esrc, edst, rowp, cur, colv);
    k_agg<4, true><<<nwb, 256, 0, stream>>>(h_buf, als, ald, rowp, colv,
                                            BI[0], GA[0], BE[0], MU[0], VA[0],
                                            xf16, nullptr, NN);
    // ---- layer 1 (K=256, HC=256, H=4)
    k_mgemm<256, 128><<<dim3(GB, 2), 256, 0, stream>>>(xf16, wTh + 32768, h_buf,
                                                       AS[1], AD[1], als, ald, 4, NN, 256);
    k_agg<4, true><<<nwb, 256, 0, stream>>>(h_buf, als, ald, rowp, colv,
                                            BI[1], GA[1], BE[1], MU[1], VA[1],
                                            xf16, nullptr, NN);
    // ---- layer 2 (K=256, HC=64, H=1)
    k_mgemm<256, 64><<<dim3(GB, 1), 256, 0, stream>>>(xf16, wTh + 98304, h_buf,
                                                      AS[2], AD[2], als, ald, 1, NN, 64);
    k_agg<1, false><<<nwb, 256, 0, stream>>>(h_buf, als, ald, rowp, colv,
                                             BI[2], GA[2], BE[2], MU[2], VA[2],
                                             nullptr, xpool, NN);

    // fused readout + MLP (512 threads: 8 node-subsets x 64 dims)
    k_poolfc<<<NGR, 512, 0, stream>>>(xpool, batch, fc1w, fc1b, fc2w, fc2b, fc3w, fc3b,
                                      (float*)d_out, NN);
    (void)in_sizes; (void)n_in; (void)out_size; (void)ws_size;
}